// Round 6
// baseline (135.888 us; speedup 1.0000x reference)
//
#include <hip/hip_runtime.h>

#define BB 2
#define NN 512
#define MM 512
#define DD 128
#define HH 256

// ---------------------------------------------------------------------------
// k_inproj: hx[b,n,h] = X[b,n,:]@W1x[:,h] + b1[h];  hy[b,m,h] = Y[b,m,:]@W1y[:,h]
// X/Y row values have block-uniform addresses -> scalar loads (s_load), no LDS.
// Also converts mask(int) -> mf(float) for k_main's scalar FMA operand.
// grid 512 x 256 (2 blocks/CU)
// ---------------------------------------------------------------------------
__global__ __launch_bounds__(256) void k_inproj(
    const float* __restrict__ X, const float* __restrict__ Y,
    const float* __restrict__ W1x, const float* __restrict__ W1y,
    const float* __restrict__ b1, const int* __restrict__ mask,
    float* __restrict__ hx, float* __restrict__ hy, float* __restrict__ mf)
{
    int blk = blockIdx.x, t = threadIdx.x;

    // mask -> float: 131072 int4 total / 512 blocks = 256 int4/block = 1/thread
    {
        int idx = blk * 256 + t;
        int4 v = ((const int4*)mask)[idx];
        ((float4*)mf)[idx] = make_float4((float)v.x, (float)v.y,
                                         (float)v.z, (float)v.w);
    }

    bool isX = blk < 256;
    const float* src = isX ? X : Y;
    const float* W   = isX ? W1x : W1y;
    float* dst       = isX ? hx : hy;
    int row0 = (isX ? blk : blk - 256) * 4;

    const float* r0 = src + (size_t)row0 * DD;   // 4 consecutive rows
    float bias = isX ? b1[t] : 0.0f;
    float a0 = bias, a1 = bias, a2 = bias, a3 = bias;

#pragma unroll 16
    for (int d = 0; d < DD; ++d) {
        float w = W[(size_t)d * HH + t];         // vector load, coalesced
        a0 = fmaf(r0[d         ], w, a0);        // uniform -> s_load
        a1 = fmaf(r0[d +   DD  ], w, a1);
        a2 = fmaf(r0[d + 2 * DD], w, a2);
        a3 = fmaf(r0[d + 3 * DD], w, a3);
    }
    dst[(size_t)(row0 + 0) * HH + t] = a0;
    dst[(size_t)(row0 + 1) * HH + t] = a1;
    dst[(size_t)(row0 + 2) * HH + t] = a2;
    dst[(size_t)(row0 + 3) * HH + t] = a3;
}

// ---------------------------------------------------------------------------
// k_main: Spart[ms][b,n,h] = sum_{m in quarter ms} mf[b,n,m]*relu(hx+hy)
// Masks read as block-uniform scalar float loads (SGPR operand of v_fmac).
// Zero LDS, zero barriers. grid 1024 x 256 (4 waves/SIMD)
// ---------------------------------------------------------------------------
__global__ __launch_bounds__(256) void k_main(
    const float* __restrict__ hx, const float* __restrict__ hy,
    const float* __restrict__ mf, float* __restrict__ Spart)
{
    int blk   = blockIdx.x;
    int ms    = blk & 3;
    int ntile = (blk >> 2) & 127;
    int b     = blk >> 9;
    int n0    = ntile * 4;
    int t     = threadIdx.x;              // h

    float hxv[4], acc[4] = {0.f, 0.f, 0.f, 0.f};
#pragma unroll
    for (int i = 0; i < 4; ++i)
        hxv[i] = hx[(size_t)(b * NN + n0 + i) * HH + t];

    const float* hyp = hy + (size_t)(b * MM + ms * 128) * HH + t;
    const float* mp  = mf + (size_t)(b * NN + n0) * MM + ms * 128;

#pragma unroll 16
    for (int m = 0; m < 128; ++m) {
        float hyv = hyp[(size_t)m * HH];           // vector, L2 hit
        float w0 = mp[m         ];                  // uniform -> s_load
        float w1 = mp[m +     MM];
        float w2 = mp[m + 2 * MM];
        float w3 = mp[m + 3 * MM];
        float t0 = fmaxf(hxv[0] + hyv, 0.f);
        float t1 = fmaxf(hxv[1] + hyv, 0.f);
        float t2 = fmaxf(hxv[2] + hyv, 0.f);
        float t3 = fmaxf(hxv[3] + hyv, 0.f);
        acc[0] = fmaf(t0, w0, acc[0]);
        acc[1] = fmaf(t1, w1, acc[1]);
        acc[2] = fmaf(t2, w2, acc[2]);
        acc[3] = fmaf(t3, w3, acc[3]);
    }
    float* sp = Spart + (size_t)ms * (BB * NN * HH) + (size_t)(b * NN + n0) * HH + t;
#pragma unroll
    for (int i = 0; i < 4; ++i) sp[(size_t)i * HH] = acc[i];
}

// ---------------------------------------------------------------------------
// k_sum: Ssum = sum of 4 Spart (to global, so k_zln can scalar-load it);
//        cntv[row] = (float)sum(mask row).
// grid 512 x 256: block = (b, n-pair)
// ---------------------------------------------------------------------------
__global__ __launch_bounds__(256) void k_sum(
    const float* __restrict__ Spart, const int* __restrict__ mask,
    float* __restrict__ Ssum, float* __restrict__ cntv)
{
    int blk = blockIdx.x;
    int b = blk >> 8, n0 = (blk & 255) * 2;
    int t = threadIdx.x, wave = t >> 6, lane = t & 63;
    const size_t P = (size_t)BB * NN * HH;

#pragma unroll
    for (int r = 0; r < 2; ++r) {
        size_t base = (size_t)(b * NN + n0 + r) * HH + t;
        Ssum[base] = Spart[base] + Spart[base + P]
                   + Spart[base + 2 * P] + Spart[base + 3 * P];
    }
    if (wave < 2) {
        const int* mrow = mask + (size_t)(b * NN + n0 + wave) * MM;
        int c = 0;
#pragma unroll
        for (int k = 0; k < 8; ++k) c += mrow[lane + k * 64];
#pragma unroll
        for (int off = 32; off; off >>= 1) c += __shfl_down(c, off);
        if (lane == 0) cntv[b * NN + n0 + wave] = (float)c;
    }
}

// ---------------------------------------------------------------------------
// layernorm helper: waves 0/1 each normalize one row of szp[2][DD] -> dst
// ---------------------------------------------------------------------------
__device__ __forceinline__ void ln_row(const float* szp_row,
                                       const float* __restrict__ g,
                                       const float* __restrict__ be,
                                       float* dst, int lane)
{
    float v0 = szp_row[lane], v1 = szp_row[lane + 64];
    float s = v0 + v1, q = v0 * v0 + v1 * v1;
#pragma unroll
    for (int off = 32; off; off >>= 1) {
        s += __shfl_down(s, off);
        q += __shfl_down(q, off);
    }
    s = __shfl(s, 0); q = __shfl(q, 0);
    float mu   = s * (1.0f / 128.0f);
    float var  = q * (1.0f / 128.0f) - mu * mu;
    float rstd = rsqrtf(var + 1e-5f);
    dst[lane]      = (v0 - mu) * rstd * g[lane]      + be[lane];
    dst[lane + 64] = (v1 - mu) * rstd * g[lane + 64] + be[lane + 64];
}

// ---------------------------------------------------------------------------
// k_zln: Zpre = X + Ssum@W2 + cnt*b2; LN0 -> zn (global)
// Ssum read scalar (s_load_dwordx8 batches); W2 is the only vector load.
// grid 512 x 256 (NT=2 rows, split-k q over h-halves)
// ---------------------------------------------------------------------------
__global__ __launch_bounds__(256) void k_zln(
    const float* __restrict__ X, const float* __restrict__ Ssum,
    const float* __restrict__ cntv,
    const float* __restrict__ W2, const float* __restrict__ b2,
    const float* __restrict__ g0, const float* __restrict__ be0,
    float* __restrict__ zn)
{
    __shared__ float scratch[2][2][DD];
    __shared__ float szp[2][DD];
    int blk = blockIdx.x;
    int b = blk >> 8, n0 = (blk & 255) * 2;
    int t = threadIdx.x, wave = t >> 6, lane = t & 63;
    int d = t & 127, q = t >> 7;

    const float* s0 = Ssum + (size_t)(b * NN + n0) * HH + q * 128;
    const float* s1 = s0 + HH;
    const float* wp = W2 + (size_t)(q * 128) * DD + d;
    float a0 = 0.f, a1 = 0.f;
#pragma unroll 8
    for (int h = 0; h < 128; ++h) {
        float w = wp[(size_t)h * DD];
        a0 = fmaf(s0[h], w, a0);          // s0/s1 uniform -> s_load
        a1 = fmaf(s1[h], w, a1);
    }
    scratch[q][0][d] = a0;
    scratch[q][1][d] = a1;
    __syncthreads();
    {
        int r = t >> 7;                    // reuse q lanes as row index
        float c = cntv[b * NN + n0 + r];
        szp[r][d] = scratch[0][r][d] + scratch[1][r][d]
                  + X[(size_t)(b * NN + n0 + r) * DD + d] + c * b2[d];
    }
    __syncthreads();
    if (wave < 2)
        ln_row(szp[wave], g0, be0, zn + (size_t)(b * NN + n0 + wave) * DD, lane);
}

// ---------------------------------------------------------------------------
// k_ff1: u = relu(zn @ Wf1 + bf1) -> global. zn scalar, Wf1 vector.
// grid 512 x 256 (2 rows/block, thread = h). No LDS, no barriers.
// ---------------------------------------------------------------------------
__global__ __launch_bounds__(256) void k_ff1(
    const float* __restrict__ zn, const float* __restrict__ Wf1,
    const float* __restrict__ bf1, float* __restrict__ u)
{
    int blk = blockIdx.x;
    int row0 = blk * 2;
    int h = threadIdx.x;
    const float* z0 = zn + (size_t)row0 * DD;
    float a0 = bf1[h], a1 = a0;
#pragma unroll 16
    for (int d = 0; d < DD; ++d) {
        float w = Wf1[(size_t)d * HH + h];
        a0 = fmaf(z0[d     ], w, a0);     // uniform -> s_load
        a1 = fmaf(z0[d + DD], w, a1);
    }
    u[(size_t)row0 * HH + h]       = fmaxf(a0, 0.f);
    u[(size_t)(row0 + 1) * HH + h] = fmaxf(a1, 0.f);
}

// ---------------------------------------------------------------------------
// k_ff2: v = u@Wf2; Z2 = zn + v + bf2; LN1 -> out
// u scalar, Wf2 vector. grid 512 x 256 (NT=2, split-k q)
// ---------------------------------------------------------------------------
__global__ __launch_bounds__(256) void k_ff2(
    const float* __restrict__ zn, const float* __restrict__ u,
    const float* __restrict__ Wf2, const float* __restrict__ bf2,
    const float* __restrict__ g1, const float* __restrict__ be1,
    float* __restrict__ out)
{
    __shared__ float scratch[2][2][DD];
    __shared__ float szp[2][DD];
    int blk = blockIdx.x;
    int row0 = blk * 2;
    int t = threadIdx.x, wave = t >> 6, lane = t & 63;
    int d = t & 127, q = t >> 7;

    const float* u0 = u + (size_t)row0 * HH + q * 128;
    const float* u1 = u0 + HH;
    const float* wp = Wf2 + (size_t)(q * 128) * DD + d;
    float a0 = 0.f, a1 = 0.f;
#pragma unroll 8
    for (int h = 0; h < 128; ++h) {
        float w = wp[(size_t)h * DD];
        a0 = fmaf(u0[h], w, a0);          // uniform -> s_load
        a1 = fmaf(u1[h], w, a1);
    }
    scratch[q][0][d] = a0;
    scratch[q][1][d] = a1;
    __syncthreads();
    {
        int r = t >> 7;
        szp[r][d] = zn[(size_t)(row0 + r) * DD + d]
                  + scratch[0][r][d] + scratch[1][r][d] + bf2[d];
    }
    __syncthreads();
    if (wave < 2)
        ln_row(szp[wave], g1, be1, out + (size_t)(row0 + wave) * DD, lane);
}

// ---------------------------------------------------------------------------
extern "C" void kernel_launch(void* const* d_in, const int* in_sizes, int n_in,
                              void* d_out, int out_size, void* d_ws, size_t ws_size,
                              hipStream_t stream)
{
    const float* X    = (const float*)d_in[0];
    const float* Y    = (const float*)d_in[1];
    const int*   mask = (const int*)d_in[2];
    const float* W1y  = (const float*)d_in[3];
    const float* W1x  = (const float*)d_in[4];
    const float* b1   = (const float*)d_in[5];
    const float* W2   = (const float*)d_in[6];
    const float* b2   = (const float*)d_in[7];
    const float* Wf1  = (const float*)d_in[8];
    const float* bf1  = (const float*)d_in[9];
    const float* Wf2  = (const float*)d_in[10];
    const float* bf2  = (const float*)d_in[11];
    const float* g0   = (const float*)d_in[12];
    const float* be0  = (const float*)d_in[13];
    const float* g1   = (const float*)d_in[14];
    const float* be1  = (const float*)d_in[15];
    float* out = (float*)d_out;

    // workspace (floats):
    float* ws   = (float*)d_ws;
    float* hx   = ws;                                  // 262144
    float* hy   = hx + (size_t)BB * NN * HH;           // 262144
    float* Sp   = hy + (size_t)BB * NN * HH;           // 4 * 262144
    float* mf   = Sp + (size_t)4 * BB * NN * HH;       // 524288
    float* Ssum = mf + (size_t)BB * NN * MM;           // 262144
    float* cntv = Ssum + (size_t)BB * NN * HH;         // 1024
    float* zn   = cntv + (size_t)BB * NN;              // 131072
    float* uu   = zn + (size_t)BB * NN * DD;           // 262144

    k_inproj<<<512, 256, 0, stream>>>(X, Y, W1x, W1y, b1, mask, hx, hy, mf);
    k_main  <<<1024, 256, 0, stream>>>(hx, hy, mf, Sp);
    k_sum   <<<512, 256, 0, stream>>>(Sp, mask, Ssum, cntv);
    k_zln   <<<512, 256, 0, stream>>>(X, Ssum, cntv, W2, b2, g0, be0, zn);
    k_ff1   <<<512, 256, 0, stream>>>(zn, Wf1, bf1, uu);
    k_ff2   <<<512, 256, 0, stream>>>(zn, uu, Wf2, bf2, g1, be1, out);
}

// Round 9
// 118.409 us; speedup vs baseline: 1.1476x; 1.1476x over previous
//
#include <hip/hip_runtime.h>

#define BB 2
#define NN 512
#define MM 512
#define DD 128
#define HH 256

// ---------------------------------------------------------------------------
// K1: hx[b,n,h] = X[b,n,:]@W1x[:,h] + b1[h];  hy[b,m,h] = Y[b,m,:]@W1y[:,h]
// Row values are block-uniform -> scalar loads; W is the coalesced vector load.
// grid 512 x 256 (2 blocks/CU)
// ---------------------------------------------------------------------------
__global__ __launch_bounds__(256) void k_inproj(
    const float* __restrict__ X, const float* __restrict__ Y,
    const float* __restrict__ W1x, const float* __restrict__ W1y,
    const float* __restrict__ b1,
    float* __restrict__ hx, float* __restrict__ hy)
{
    int blk = blockIdx.x, t = threadIdx.x;
    bool isX = blk < 256;
    const float* src = isX ? X : Y;
    const float* W   = isX ? W1x : W1y;
    float* dst       = isX ? hx : hy;
    int row0 = (isX ? blk : blk - 256) * 4;

    const float* r0 = src + (size_t)row0 * DD;   // 4 consecutive rows
    float bias = isX ? b1[t] : 0.0f;
    float a0 = bias, a1 = bias, a2 = bias, a3 = bias;

#pragma unroll 16
    for (int d = 0; d < DD; ++d) {
        float w = W[(size_t)d * HH + t];         // vector load, coalesced
        a0 = fmaf(r0[d         ], w, a0);        // uniform -> s_load
        a1 = fmaf(r0[d +   DD  ], w, a1);
        a2 = fmaf(r0[d + 2 * DD], w, a2);
        a3 = fmaf(r0[d + 3 * DD], w, a3);
    }
    dst[(size_t)(row0 + 0) * HH + t] = a0;
    dst[(size_t)(row0 + 1) * HH + t] = a1;
    dst[(size_t)(row0 + 2) * HH + t] = a2;
    dst[(size_t)(row0 + 3) * HH + t] = a3;
}

// ---------------------------------------------------------------------------
// K2: everything else, fused per 4-row n-tile. grid 256 x 512 (8 waves/block,
// 1 block/CU -> 2 waves/SIMD). All intermediates in LDS; no global round-trips.
//  A: masks -> LDS float [m][r]; per-row counts (shuffle reduce)
//  B: S[r][h] = sum_m mf*relu(hx+hy), m split over thread-halves, LDS merge
//  C: Zpre = X + S@W2 + cnt*b2 (split-k q=h/64); LN0 -> znT[d][r]
//  D: u = relu(zn@Wf1 + bf1) (split-k dq=d/64) -> suT[h][r]
//  E: Z2 = zn + u@Wf2 + bf2 (split-k); LN1 -> out
// ---------------------------------------------------------------------------
__global__ __launch_bounds__(512) void k_fused(
    const float* __restrict__ X, const float* __restrict__ hx,
    const float* __restrict__ hy, const int* __restrict__ mask,
    const float* __restrict__ W2, const float* __restrict__ b2,
    const float* __restrict__ Wf1, const float* __restrict__ bf1,
    const float* __restrict__ Wf2, const float* __restrict__ bf2,
    const float* __restrict__ g0, const float* __restrict__ be0,
    const float* __restrict__ g1, const float* __restrict__ be1,
    float* __restrict__ out)
{
    __shared__ float smf[MM][4];        // 8 KB  [m][r] mask floats
    __shared__ float sSp[2][HH][4];     // 8 KB  [mhalf][h][r] partial S
    __shared__ float sST[HH][4];        // 4 KB  [h][r] merged S
    __shared__ float scratch[4][4][DD]; // 8 KB  [q][r][d] split-k partials
    __shared__ float znT[DD][4];        // 2 KB  [d][r] LN0 output
    __shared__ float sp2[2][HH][4];     // 8 KB  [dq][h][r] FF1 partials
    __shared__ float suT[HH][4];        // 4 KB  [h][r] relu'd hidden
    __shared__ float srow[4][DD];       // 2 KB  LN workspace
    __shared__ float scnt[4];

    int blk = blockIdx.x;
    int b = blk >> 7, n0 = (blk & 127) * 4;
    int t = threadIdx.x;
    int wave = t >> 6, lane = t & 63;

    // ---- Phase A: masks to LDS (thread t = column m), counts via waves 0-3
    {
        const int* mp = mask + (size_t)(b * NN + n0) * MM + t;
#pragma unroll
        for (int r = 0; r < 4; ++r)
            smf[t][r] = (float)mp[(size_t)r * MM];
    }
    if (wave < 4) {
        const int* mrow = mask + (size_t)(b * NN + n0 + wave) * MM;
        int c = 0;
#pragma unroll
        for (int k = 0; k < 8; ++k) c += mrow[lane + k * 64];
#pragma unroll
        for (int off = 32; off; off >>= 1) c += __shfl_down(c, off);
        if (lane == 0) scnt[wave] = (float)c;
    }
    __syncthreads();

    // ---- Phase B: masked-relu partial sums over this thread's m-half
    {
        int h = t & 255, mh = t >> 8;
        float hxv[4];
#pragma unroll
        for (int r = 0; r < 4; ++r)
            hxv[r] = hx[(size_t)(b * NN + n0 + r) * HH + h];
        const float* hyp = hy + ((size_t)b * MM + mh * 256) * HH + h;
        float a0 = 0.f, a1 = 0.f, a2 = 0.f, a3 = 0.f;
#pragma unroll 16
        for (int m = 0; m < 256; ++m) {
            float hyv = hyp[(size_t)m * HH];                 // L2 hit
            float4 m4 = *(const float4*)&smf[mh * 256 + m][0]; // LDS broadcast
            a0 = fmaf(fmaxf(hxv[0] + hyv, 0.f), m4.x, a0);
            a1 = fmaf(fmaxf(hxv[1] + hyv, 0.f), m4.y, a1);
            a2 = fmaf(fmaxf(hxv[2] + hyv, 0.f), m4.z, a2);
            a3 = fmaf(fmaxf(hxv[3] + hyv, 0.f), m4.w, a3);
        }
        *(float4*)&sSp[mh][h][0] = make_float4(a0, a1, a2, a3);
    }
    __syncthreads();
#pragma unroll
    for (int k = 0; k < 2; ++k) {
        int v = t + k * 512;              // 0..1023 over (h,r)
        int h = v >> 2, r = v & 3;
        sST[h][r] = sSp[0][h][r] + sSp[1][h][r];
    }
    __syncthreads();

    // ---- Phase C: Zpre = X + S@W2 + cnt*b2, then LN0
    {
        int d = t & 127, q = t >> 7;      // q = h-quarter, uniform per wave-pair
        const float* wp = W2 + (size_t)(q * 64) * DD + d;
        float a0 = 0.f, a1 = 0.f, a2 = 0.f, a3 = 0.f;
#pragma unroll 8
        for (int hh = 0; hh < 64; ++hh) {
            float w = wp[(size_t)hh * DD];
            float4 s4 = *(const float4*)&sST[q * 64 + hh][0];  // broadcast
            a0 = fmaf(s4.x, w, a0); a1 = fmaf(s4.y, w, a1);
            a2 = fmaf(s4.z, w, a2); a3 = fmaf(s4.w, w, a3);
        }
        scratch[q][0][d] = a0; scratch[q][1][d] = a1;
        scratch[q][2][d] = a2; scratch[q][3][d] = a3;
    }
    __syncthreads();
    {
        int r = t >> 7, d = t & 127;      // 512 threads = 4 rows x 128 d
        srow[r][d] = scratch[0][r][d] + scratch[1][r][d]
                   + scratch[2][r][d] + scratch[3][r][d]
                   + X[(size_t)(b * NN + n0 + r) * DD + d] + scnt[r] * b2[d];
    }
    __syncthreads();
    if (wave < 4) {                        // LN0: wave w -> row w
        float v0 = srow[wave][lane], v1 = srow[wave][lane + 64];
        float s = v0 + v1, q2 = v0 * v0 + v1 * v1;
#pragma unroll
        for (int off = 32; off; off >>= 1) {
            s += __shfl_down(s, off); q2 += __shfl_down(q2, off);
        }
        s = __shfl(s, 0); q2 = __shfl(q2, 0);
        float mu   = s * (1.0f / 128.0f);
        float var  = q2 * (1.0f / 128.0f) - mu * mu;
        float rstd = rsqrtf(var + 1e-5f);
        znT[lane][wave]      = (v0 - mu) * rstd * g0[lane]      + be0[lane];
        znT[lane + 64][wave] = (v1 - mu) * rstd * g0[lane + 64] + be0[lane + 64];
    }
    __syncthreads();

    // ---- Phase D: u = relu(zn@Wf1 + bf1)
    {
        int h = t & 255, dq = t >> 8;     // dq = d-half
        float bias = dq ? 0.f : bf1[h];
        float a0 = bias, a1 = bias, a2 = bias, a3 = bias;
        const float* wp = Wf1 + (size_t)(dq * 64) * HH + h;
#pragma unroll 8
        for (int dd = 0; dd < 64; ++dd) {
            float w = wp[(size_t)dd * HH];
            float4 z4 = *(const float4*)&znT[dq * 64 + dd][0];  // broadcast
            a0 = fmaf(z4.x, w, a0); a1 = fmaf(z4.y, w, a1);
            a2 = fmaf(z4.z, w, a2); a3 = fmaf(z4.w, w, a3);
        }
        *(float4*)&sp2[dq][h][0] = make_float4(a0, a1, a2, a3);
    }
    __syncthreads();
#pragma unroll
    for (int k = 0; k < 2; ++k) {
        int v = t + k * 512;
        int h = v >> 2, r = v & 3;
        suT[h][r] = fmaxf(sp2[0][h][r] + sp2[1][h][r], 0.f);
    }
    __syncthreads();

    // ---- Phase E: Z2 = zn + u@Wf2 + bf2, then LN1 -> out
    {
        int d = t & 127, q = t >> 7;
        const float* wp = Wf2 + (size_t)(q * 64) * DD + d;
        float a0 = 0.f, a1 = 0.f, a2 = 0.f, a3 = 0.f;
#pragma unroll 8
        for (int hh = 0; hh < 64; ++hh) {
            float w = wp[(size_t)hh * DD];
            float4 u4 = *(const float4*)&suT[q * 64 + hh][0];   // broadcast
            a0 = fmaf(u4.x, w, a0); a1 = fmaf(u4.y, w, a1);
            a2 = fmaf(u4.z, w, a2); a3 = fmaf(u4.w, w, a3);
        }
        scratch[q][0][d] = a0; scratch[q][1][d] = a1;
        scratch[q][2][d] = a2; scratch[q][3][d] = a3;
    }
    __syncthreads();
    {
        int r = t >> 7, d = t & 127;
        srow[r][d] = znT[d][r] + bf2[d]
                   + scratch[0][r][d] + scratch[1][r][d]
                   + scratch[2][r][d] + scratch[3][r][d];
    }
    __syncthreads();
    if (wave < 4) {                        // LN1: wave w -> row w
        float v0 = srow[wave][lane], v1 = srow[wave][lane + 64];
        float s = v0 + v1, q2 = v0 * v0 + v1 * v1;
#pragma unroll
        for (int off = 32; off; off >>= 1) {
            s += __shfl_down(s, off); q2 += __shfl_down(q2, off);
        }
        s = __shfl(s, 0); q2 = __shfl(q2, 0);
        float mu   = s * (1.0f / 128.0f);
        float var  = q2 * (1.0f / 128.0f) - mu * mu;
        float rstd = rsqrtf(var + 1e-5f);
        size_t row = (size_t)(b * NN + n0 + wave) * DD;
        out[row + lane]      = (v0 - mu) * rstd * g1[lane]      + be1[lane];
        out[row + lane + 64] = (v1 - mu) * rstd * g1[lane + 64] + be1[lane + 64];
    }
}

// ---------------------------------------------------------------------------
extern "C" void kernel_launch(void* const* d_in, const int* in_sizes, int n_in,
                              void* d_out, int out_size, void* d_ws, size_t ws_size,
                              hipStream_t stream)
{
    const float* X    = (const float*)d_in[0];
    const float* Y    = (const float*)d_in[1];
    const int*   mask = (const int*)d_in[2];
    const float* W1y  = (const float*)d_in[3];
    const float* W1x  = (const float*)d_in[4];
    const float* b1   = (const float*)d_in[5];
    const float* W2   = (const float*)d_in[6];
    const float* b2   = (const float*)d_in[7];
    const float* Wf1  = (const float*)d_in[8];
    const float* bf1  = (const float*)d_in[9];
    const float* Wf2  = (const float*)d_in[10];
    const float* bf2  = (const float*)d_in[11];
    const float* g0   = (const float*)d_in[12];
    const float* be0  = (const float*)d_in[13];
    const float* g1   = (const float*)d_in[14];
    const float* be1  = (const float*)d_in[15];
    float* out = (float*)d_out;

    // workspace (floats): hx[B*N*H] | hy[B*M*H]  (2 MB total)
    float* ws = (float*)d_ws;
    float* hx = ws;
    float* hy = ws + (size_t)BB * NN * HH;

    k_inproj<<<512, 256, 0, stream>>>(X, Y, W1x, W1y, b1, hx, hy);
    k_fused <<<256, 512, 0, stream>>>(X, hx, hy, mask, W2, b2, Wf1, bf1,
                                      Wf2, bf2, g0, be0, g1, be1, out);
}